// Round 5
// baseline (920.025 us; speedup 1.0000x reference)
//
#include <hip/hip_runtime.h>
#include <hip/hip_cooperative_groups.h>

namespace cg = cooperative_groups;

typedef __attribute__((ext_vector_type(8))) short short8;
typedef __attribute__((ext_vector_type(4))) float f32x4;
typedef __attribute__((ext_vector_type(4))) float fvec4;
typedef __attribute__((ext_vector_type(4))) unsigned short us4;

#define T_ 2048
#define D_ 512
#define SC_ 0.04419417382415922f   // 1/sqrt(512)

__device__ __forceinline__ unsigned short f2bf(float f) {
    unsigned int u = __float_as_uint(f);
    u += 0x7fffu + ((u >> 16) & 1u);
    return (unsigned short)(u >> 16);
}

// async global->LDS, 16B per lane; LDS dest = wave-uniform base + lane*16
__device__ __forceinline__ void gload16(const void* g, void* l) {
    __builtin_amdgcn_global_load_lds((const __attribute__((address_space(1))) unsigned int*)g,
                                     (__attribute__((address_space(3))) unsigned int*)l,
                                     16, 0, 0);
}

// ---------------------------------------------------------------- shared mem
struct __align__(16) SMem {
    union {
        unsigned short At[128 * 32];   // 8 KB GEMM A-tile
        float s[2048];                 // softmax row buffer
        float wt[32][33];              // transpose tile (padded)
    };
    unsigned short Bt[128 * 32];       // 8 KB GEMM B-tile
    float red[8];
};

// ---------------------------------------------------------------- GEMM core
// LDS tile: element (row,c) in 16B chunk (row, (c/8) ^ ((row>>1)&3)) — XOR
// swizzle spreads ds_read_b128 across all 8 bank-groups.
__device__ __forceinline__ void gemm_core(const unsigned short* __restrict__ A, long lda,
                                          const unsigned short* __restrict__ B, long ldb,
                                          int kmax, SMem& sm, f32x4 (&acc)[4][4]) {
    const int tid = threadIdx.x;
    const int wid = tid >> 6;
    const int lane = tid & 63;
    const int quad = lane >> 4;
    const int lr = lane & 15;
    const int wm = (wid & 1) * 64;
    const int wn = (wid >> 1) * 64;
#pragma unroll
    for (int r = 0; r < 4; ++r)
#pragma unroll
        for (int c = 0; c < 4; ++c) acc[r][c] = (f32x4){0.f, 0.f, 0.f, 0.f};

    const int sr = tid >> 2;                              // staging row 0..63
    const int sc = (((tid & 3) ^ ((sr >> 1) & 3))) * 8;   // swizzled source chunk
    const unsigned short* Ag = A + (long)sr * lda + sc;
    const unsigned short* Bg = B + (long)sr * ldb + sc;
    unsigned short* lA0 = &sm.At[wid * 512];
    unsigned short* lA1 = &sm.At[2048 + wid * 512];
    unsigned short* lB0 = &sm.Bt[wid * 512];
    unsigned short* lB1 = &sm.Bt[2048 + wid * 512];

    for (int kk = 0; kk < kmax; kk += 32) {
        gload16(Ag + kk, lA0);
        gload16(Ag + 64L * lda + kk, lA1);
        gload16(Bg + kk, lB0);
        gload16(Bg + 64L * ldb + kk, lB1);
        __syncthreads();
        short8 av[4], bv[4];
#pragma unroll
        for (int r = 0; r < 4; ++r) {
            const int row = wm + r * 16 + lr;
            av[r] = *(const short8*)&sm.At[row * 32 + ((quad ^ ((row >> 1) & 3)) * 8)];
        }
#pragma unroll
        for (int c = 0; c < 4; ++c) {
            const int row = wn + c * 16 + lr;
            bv[c] = *(const short8*)&sm.Bt[row * 32 + ((quad ^ ((row >> 1) & 3)) * 8)];
        }
#pragma unroll
        for (int r = 0; r < 4; ++r)
#pragma unroll
            for (int c = 0; c < 4; ++c)
                acc[r][c] = __builtin_amdgcn_mfma_f32_16x16x32_bf16(av[r], bv[c], acc[r][c], 0, 0, 0);
        __syncthreads();
    }
}

// ---------------------------------------------------------------- mega kernel
__global__ __launch_bounds__(256) void mega(
    const float* __restrict__ in_f,
    const float* __restrict__ Wq, const float* __restrict__ Wk,
    const float* __restrict__ Wv, const float* __restrict__ Wr,
    const float* __restrict__ cb, const float* __restrict__ rb,
    float* __restrict__ out,
    unsigned short* __restrict__ in_bf,
    unsigned short* __restrict__ WqT, unsigned short* __restrict__ WkT,
    unsigned short* __restrict__ WvT, unsigned short* __restrict__ WrT,
    unsigned short* __restrict__ pe,
    unsigned short* __restrict__ qc, unsigned short* __restrict__ qr,
    unsigned short* __restrict__ kbf, unsigned short* __restrict__ vT,
    unsigned short* __restrict__ rk,
    float* __restrict__ C8, float* __restrict__ R8)
{
    __shared__ SMem sm;
    cg::grid_group grid = cg::this_grid();
    const int nb = gridDim.x;
    const int tid = threadIdx.x;
    const int wid = tid >> 6;
    const int lane = tid & 63;
    const int quad = lane >> 4;
    const int lr = lane & 15;
    const int wm = (wid & 1) * 64;
    const int wn = (wid >> 1) * 64;
    const long TD = (long)T_ * D_;
    const long DT = (long)D_ * T_;
    f32x4 acc[4][4];

    // ---- P0a: f32 -> bf16 convert of inputs (2,097,152 us4 chunks)
    for (int idx = blockIdx.x * 256 + tid; idx < 2097152; idx += nb * 256) {
        fvec4 v = ((const fvec4*)in_f)[idx];
        us4 o;
        o.x = f2bf(v.x); o.y = f2bf(v.y); o.z = f2bf(v.z); o.w = f2bf(v.w);
        ((us4*)in_bf)[idx] = o;
    }
    // ---- P0b: weight transposes via LDS 32x32 tiles (coalesced both sides)
    for (int t = blockIdx.x; t < 1024; t += nb) {
        const int w = t >> 8, tile = t & 255;
        const int tr = (tile >> 4) * 32, tc = (tile & 15) * 32;
        const float* W = (w == 0) ? Wq : (w == 1) ? Wk : (w == 2) ? Wv : Wr;
        unsigned short* WT = (w == 0) ? WqT : (w == 1) ? WkT : (w == 2) ? WvT : WrT;
        const int r0 = tid >> 5, c0 = tid & 31;
        __syncthreads();                    // LDS reuse across iterations
#pragma unroll
        for (int p = 0; p < 4; ++p)
            sm.wt[r0 + 8 * p][c0] = W[(long)(tr + r0 + 8 * p) * 512 + tc + c0];
        __syncthreads();
#pragma unroll
        for (int p = 0; p < 4; ++p)
            WT[(long)(tc + r0 + 8 * p) * 512 + tr + c0] = f2bf(sm.wt[c0][r0 + 8 * p]);
    }
    // ---- P0c: sinusoidal pe table (262,144 us4 chunks)
    for (int idx = blockIdx.x * 256 + tid; idx < 262144; idx += nb * 256) {
        const int o = idx * 4;
        const int rpos = o >> 9;
        us4 ov;
#pragma unroll
        for (int e = 0; e < 4; ++e) {
            const int c = (o + e) & 511;
            const int ci = (c < 256) ? c : c - 256;
            const float dv = expf((float)ci * -0.03611898183128701f);  // -log(1e4)/255
            const float ang = (float)rpos * dv;
            ((unsigned short*)&ov)[e] = f2bf((c < 256) ? sinf(ang) : cosf(ang));
        }
        ((us4*)pe)[idx] = ov;
    }
    __threadfence(); grid.sync(); __threadfence();

    // ---- P1: projections (1600 tile jobs)
    for (int t = blockIdx.x; t < 1600; t += nb) {
        if (t < 1024) {                           // qc/qr (t<512), k (t<1024)
            const int r = t & 511;
            const int it = r >> 2, jt = r & 3;
            const unsigned short* Bw = (t < 512) ? WqT : WkT;
            gemm_core(in_bf + (long)it * 128 * 512, 512, Bw + (long)jt * 128 * 512, 512, 512, sm, acc);
            const int i0 = it * 128, j0 = jt * 128;
#pragma unroll
            for (int r2 = 0; r2 < 4; ++r2)
#pragma unroll
                for (int c2 = 0; c2 < 4; ++c2) {
                    const int gi = i0 + wm + r2 * 16 + quad * 4;
                    const int gj = j0 + wn + c2 * 16 + lr;
#pragma unroll
                    for (int tt = 0; tt < 4; ++tt) {
                        const float v = acc[r2][c2][tt];
                        const long row = gi + tt;
                        if (t < 512) {
                            qc[row * 512 + gj] = f2bf(v + cb[gj]);
                            qr[row * 512 + gj] = f2bf(v + rb[gj]);
                        } else {
                            kbf[row * 512 + gj] = f2bf(v);
                        }
                    }
                }
        } else if (t < 1536) {                    // vT[b] = Wv^T @ in[b]^T
            const int r = t - 1024;
            const int z = r >> 6, rr = r & 63;
            const int it = rr >> 4, jt = rr & 15;
            const int i0 = it * 128, j0 = jt * 128;
            gemm_core(WvT + (long)i0 * 512, 512, in_bf + (long)z * TD + (long)j0 * 512, 512, 512, sm, acc);
#pragma unroll
            for (int r2 = 0; r2 < 4; ++r2)
#pragma unroll
                for (int c2 = 0; c2 < 4; ++c2) {
                    const int gi = i0 + wm + r2 * 16 + quad * 4;
                    const int gj = j0 + wn + c2 * 16 + lr;
#pragma unroll
                    for (int tt = 0; tt < 4; ++tt)
                        vT[(long)z * DT + (long)(gi + tt) * 2048 + gj] = f2bf(acc[r2][c2][tt]);
                }
        } else {                                  // rk = pe @ Wrel
            const int r = t - 1536;
            const int it = r >> 2, jt = r & 3;
            const int i0 = it * 128, j0 = jt * 128;
            gemm_core(pe + (long)i0 * 512, 512, WrT + (long)j0 * 512, 512, 512, sm, acc);
#pragma unroll
            for (int r2 = 0; r2 < 4; ++r2)
#pragma unroll
                for (int c2 = 0; c2 < 4; ++c2) {
                    const int gi = i0 + wm + r2 * 16 + quad * 4;
                    const int gj = j0 + wn + c2 * 16 + lr;
#pragma unroll
                    for (int tt = 0; tt < 4; ++tt)
                        rk[(long)(gi + tt) * 512 + gj] = f2bf(acc[r2][c2][tt]);
                }
        }
    }
    __threadfence(); grid.sync(); __threadfence();

    // ---- P2: content scores -> C8 (pre-scaled) and rel scores -> R8 (raw).
    // Independent outputs, one phase, 2176 jobs.
    for (int t = blockIdx.x; t < 2176; t += nb) {
        if (t < 1088) {
            const int z = t / 136;
            const int r = t - z * 136;
            int a = (int)((sqrtf(8.f * (float)r + 1.f) - 1.f) * 0.5f);
            if ((a + 1) * (a + 2) / 2 <= r) ++a;
            if (a * (a + 1) / 2 > r) --a;
            const int b = r - a * (a + 1) / 2;    // b <= a (causal tiles)
            const int i0 = a * 128, j0 = b * 128;
            gemm_core(qc + (long)z * TD + (long)i0 * 512, 512,
                      kbf + (long)z * TD + (long)j0 * 512, 512, 512, sm, acc);
            float* Cf = C8 + (long)z * 4194304L;
#pragma unroll
            for (int r2 = 0; r2 < 4; ++r2)
#pragma unroll
                for (int c2 = 0; c2 < 4; ++c2) {
                    const int gi = i0 + wm + r2 * 16 + quad * 4;
                    const int gj = j0 + wn + c2 * 16 + lr;
#pragma unroll
                    for (int tt = 0; tt < 4; ++tt)
                        Cf[(long)(gi + tt) * 2048 + gj] = acc[r2][c2][tt] * SC_;
                }
        } else {
            const int t2 = t - 1088;
            const int z = t2 / 136;
            const int r = t2 - z * 136;
            int u = (int)((sqrtf(8.f * (float)r + 1.f) - 1.f) * 0.5f);
            if ((u + 1) * (u + 2) / 2 <= r) ++u;
            if (u * (u + 1) / 2 > r) --u;
            const int v2 = r - u * (u + 1) / 2;   // v2 <= u
            const int a = u, b = 15 - u + v2;     // tiles with p >= T-1-i coverage
            const int i0 = a * 128, p0 = b * 128;
            gemm_core(qr + (long)z * TD + (long)i0 * 512, 512,
                      rk + (long)p0 * 512, 512, 512, sm, acc);
            float* Rf = R8 + (long)z * 4194304L;
#pragma unroll
            for (int r2 = 0; r2 < 4; ++r2)
#pragma unroll
                for (int c2 = 0; c2 < 4; ++c2) {
                    const int gi = i0 + wm + r2 * 16 + quad * 4;
                    const int gp = p0 + wn + c2 * 16 + lr;
#pragma unroll
                    for (int tt = 0; tt < 4; ++tt)
                        Rf[(long)(gi + tt) * 2048 + gp] = acc[r2][c2][tt];   // raw, no RMW
                }
        }
    }
    __threadfence(); grid.sync(); __threadfence();

    // ---- P3: row softmax. S[i,j] = C8[i,j] + SC*R8[i, j + (T-1-i)]; P bf16 in place.
    for (int t = blockIdx.x; t < 16384; t += nb) {
        __syncthreads();                          // protect sm.s reuse
        const int z = t >> 11;
        const int i = t & 2047;
        const int n = i + 1;
        float* Cm = C8 + (long)z * 4194304L;
        float* crow = Cm + (long)i * 2048;
        const float* rrow = R8 + (long)z * 4194304L + (long)i * 2048 + (2047 - i);
        float lmax = -3.0e38f;
        for (int j = tid; j < n; j += 256) {
            float v = crow[j] + rrow[j] * SC_;
            sm.s[j] = v; lmax = fmaxf(lmax, v);
        }
        for (int o = 32; o; o >>= 1) lmax = fmaxf(lmax, __shfl_down(lmax, o));
        if (lane == 0) sm.red[wid] = lmax;
        __syncthreads();
        if (tid == 0) sm.red[4] = fmaxf(fmaxf(sm.red[0], sm.red[1]), fmaxf(sm.red[2], sm.red[3]));
        __syncthreads();
        const float m = sm.red[4];
        float lsum = 0.f;
        for (int j = tid; j < n; j += 256) { float e = __expf(sm.s[j] - m); sm.s[j] = e; lsum += e; }
        for (int o = 32; o; o >>= 1) lsum += __shfl_down(lsum, o);
        if (lane == 0) sm.red[wid] = lsum;
        __syncthreads();
        if (tid == 0) sm.red[4] = 1.0f / (sm.red[0] + sm.red[1] + sm.red[2] + sm.red[3]);
        __syncthreads();
        const float inv = sm.red[4];
        unsigned short* P = (unsigned short*)Cm;  // bf16 row stride 4096
        const int iend = ((i >> 7) + 1) << 7;     // zero-pad to 128-tile edge
        for (int j = tid; j < iend; j += 256) {
            const float pv = (j < n) ? sm.s[j] * inv : 0.f;
            P[(long)i * 4096 + j] = f2bf(pv);
        }
    }
    __threadfence(); grid.sync(); __threadfence();

    // ---- P4: out = P @ V (512 jobs; big K-tiles first, big/small halves)
    for (int t = blockIdx.x; t < 512; t += nb) {
        const int half = t >> 8;
        const int a4 = t & 255;
        const int z = a4 >> 5;
        const int idx = a4 & 31;
        const int it = half ? (idx >> 2) : (15 - (idx >> 2));
        const int jt = idx & 3;
        const int i0 = it * 128, j0 = jt * 128;
        const int kmax = i0 + 128;                // causal K-limit
        gemm_core((const unsigned short*)(C8 + (long)z * 4194304L) + (long)i0 * 4096, 4096,
                  vT + (long)z * DT + (long)j0 * 2048, 2048, kmax, sm, acc);
#pragma unroll
        for (int r2 = 0; r2 < 4; ++r2)
#pragma unroll
            for (int c2 = 0; c2 < 4; ++c2) {
                const int gi = i0 + wm + r2 * 16 + quad * 4;
                const int gj = j0 + wn + c2 * 16 + lr;
#pragma unroll
                for (int tt = 0; tt < 4; ++tt)
                    out[(long)z * TD + (long)(gi + tt) * 512 + gj] = acc[r2][c2][tt];
            }
    }
}

// ---------------------------------------------------------------- launcher
extern "C" void kernel_launch(void* const* d_in, const int* in_sizes, int n_in,
                              void* d_out, int out_size, void* d_ws, size_t ws_size,
                              hipStream_t stream) {
    (void)in_sizes; (void)n_in; (void)out_size; (void)ws_size;
    const float* inputs = (const float*)d_in[0];
    const float* Wq = (const float*)d_in[1];
    const float* Wk = (const float*)d_in[2];
    const float* Wv = (const float*)d_in[3];
    const float* Wrel = (const float*)d_in[4];
    const float* cb = (const float*)d_in[5];
    const float* rb = (const float*)d_in[6];
    float* out = (float*)d_out;

    // workspace layout (~357 MB)
    char* ws = (char*)d_ws;
    unsigned short* in_bf = (unsigned short*)ws;                   // 16384x512
    unsigned short* WqT = (unsigned short*)(ws + 16777216);
    unsigned short* WkT = WqT + 262144;
    unsigned short* WvT = WkT + 262144;
    unsigned short* WrT = WvT + 262144;
    unsigned short* pe  = WrT + 262144;                            // 2048x512
    unsigned short* qc  = pe + 1048576;                            // 16384x512
    unsigned short* qr  = qc + 8388608;
    unsigned short* kbf = qr + 8388608;
    unsigned short* vT  = kbf + 8388608;                           // 8 x 512x2048
    unsigned short* rk  = vT + 8388608;                            // 2048x512
    float* C8 = (float*)(rk + 1048576);                            // 8 x 2048x2048 f32
    float* R8 = C8 + 33554432;                                     // 8 x 2048x2048 f32

    int occ = 0;
    hipError_t e = hipOccupancyMaxActiveBlocksPerMultiprocessor(&occ, (const void*)mega, 256, 0);
    if (e != hipSuccess || occ < 1) occ = 1;
    if (occ > 8) occ = 8;
    int nblocks = occ * 256;

    void* args[] = {(void*)&inputs, (void*)&Wq, (void*)&Wk, (void*)&Wv, (void*)&Wrel,
                    (void*)&cb, (void*)&rb, (void*)&out,
                    (void*)&in_bf, (void*)&WqT, (void*)&WkT, (void*)&WvT, (void*)&WrT,
                    (void*)&pe, (void*)&qc, (void*)&qr, (void*)&kbf, (void*)&vT,
                    (void*)&rk, (void*)&C8, (void*)&R8};
    hipLaunchCooperativeKernel((const void*)mega, dim3(nblocks), dim3(256), args, 0, stream);
}

// Round 6
// 391.729 us; speedup vs baseline: 2.3486x; 2.3486x over previous
//
#include <hip/hip_runtime.h>

typedef __attribute__((ext_vector_type(8))) short short8;
typedef __attribute__((ext_vector_type(4))) float f32x4;
typedef __attribute__((ext_vector_type(4))) float fvec4;
typedef __attribute__((ext_vector_type(4))) unsigned short us4;

#define T_ 2048
#define D_ 512
#define SC_ 0.04419417382415922f   // 1/sqrt(512)

__device__ __forceinline__ unsigned short f2bf(float f) {
    unsigned int u = __float_as_uint(f);
    u += 0x7fffu + ((u >> 16) & 1u);
    return (unsigned short)(u >> 16);
}

// async global->LDS, 16B per lane; LDS dest = wave-uniform base + lane*16
__device__ __forceinline__ void gload16(const void* g, void* l) {
    __builtin_amdgcn_global_load_lds((const __attribute__((address_space(1))) unsigned int*)g,
                                     (__attribute__((address_space(3))) unsigned int*)l,
                                     16, 0, 0);
}

// ---------------------------------------------------------------- merged prep
// blocks [0,8192): f32->bf16 convert; [8192,9216): weight transpose tiles;
// [9216,10240): sinusoidal pe table.
__global__ __launch_bounds__(256) void prep_all(
    const float* __restrict__ in_f,
    const float* __restrict__ Wq, const float* __restrict__ Wk,
    const float* __restrict__ Wv, const float* __restrict__ Wr,
    unsigned short* __restrict__ in_bf,
    unsigned short* __restrict__ WqT, unsigned short* __restrict__ WkT,
    unsigned short* __restrict__ WvT, unsigned short* __restrict__ WrT,
    unsigned short* __restrict__ pe)
{
    const int bb = blockIdx.x;
    const int tid = threadIdx.x;
    if (bb < 8192) {
        const int idx = bb * 256 + tid;
        fvec4 v = ((const fvec4*)in_f)[idx];
        us4 o;
        o.x = f2bf(v.x); o.y = f2bf(v.y); o.z = f2bf(v.z); o.w = f2bf(v.w);
        ((us4*)in_bf)[idx] = o;
    } else if (bb < 9216) {
        __shared__ float wt[32][33];              // padded: no bank conflicts
        const int t = bb - 8192;                  // 0..1023
        const int w = t >> 8, tile = t & 255;
        const int tr = (tile >> 4) * 32, tc = (tile & 15) * 32;
        const float* W = (w == 0) ? Wq : (w == 1) ? Wk : (w == 2) ? Wv : Wr;
        unsigned short* WT = (w == 0) ? WqT : (w == 1) ? WkT : (w == 2) ? WvT : WrT;
        const int r0 = tid >> 5, c0 = tid & 31;
#pragma unroll
        for (int p = 0; p < 4; ++p)
            wt[r0 + 8 * p][c0] = W[(long)(tr + r0 + 8 * p) * 512 + tc + c0];
        __syncthreads();
#pragma unroll
        for (int p = 0; p < 4; ++p)
            WT[(long)(tc + r0 + 8 * p) * 512 + tr + c0] = f2bf(wt[c0][r0 + 8 * p]);
    } else {
        const int idx = (bb - 9216) * 256 + tid;  // 0..262143 us4 chunks
        const int o = idx * 4;
        const int rpos = o >> 9;
        us4 ov;
#pragma unroll
        for (int e = 0; e < 4; ++e) {
            const int c = (o + e) & 511;
            const int ci = (c < 256) ? c : c - 256;
            const float dv = expf((float)ci * -0.03611898183128701f);  // -log(1e4)/255
            const float ang = (float)rpos * dv;
            ((unsigned short*)&ov)[e] = f2bf((c < 256) ? sinf(ang) : cosf(ang));
        }
        ((us4*)pe)[idx] = ov;
    }
}

// ---------------------------------------------------------------- GEMM core
// BK=64. LDS tile [128][64] bf16 (16 KB each). Element (row,c) lives in 16B
// chunk (row, (c/8) ^ (row&7)) — XOR swizzle keeps ds_read_b128 at 2-way max
// bank aliasing (free, m136) and staging wave-uniform-dest compatible.
struct __align__(16) SMem {
    unsigned short At[128 * 64];   // 16 KB
    unsigned short Bt[128 * 64];   // 16 KB
};

__device__ __forceinline__ void gemm_core(const unsigned short* __restrict__ A, long lda,
                                          const unsigned short* __restrict__ B, long ldb,
                                          int kmax, SMem& sm, f32x4 (&acc)[4][4]) {
    const int tid = threadIdx.x;
    const int wid = tid >> 6;
    const int lane = tid & 63;
    const int quad = lane >> 4;
    const int lr = lane & 15;
    const int wm = (wid & 1) * 64;
    const int wn = (wid >> 1) * 64;
#pragma unroll
    for (int r = 0; r < 4; ++r)
#pragma unroll
        for (int c = 0; c < 4; ++c) acc[r][c] = (f32x4){0.f, 0.f, 0.f, 0.f};

    const int sr = tid >> 3;                             // staging row 0..31
    const int l8 = ((tid & 7) ^ (sr & 7)) * 8;           // swizzled source chunk
    const unsigned short* Ag = A + (long)sr * lda + l8;
    const unsigned short* Bg = B + (long)sr * ldb + l8;

    for (int kk = 0; kk < kmax; kk += 64) {
#pragma unroll
        for (int c = 0; c < 4; ++c) {                    // rows 32c..32c+31
            gload16(Ag + (long)(32 * c) * lda + kk, &sm.At[c * 2048 + wid * 512]);
            gload16(Bg + (long)(32 * c) * ldb + kk, &sm.Bt[c * 2048 + wid * 512]);
        }
        __syncthreads();
#pragma unroll
        for (int ks = 0; ks < 2; ++ks) {
            short8 av[4], bv[4];
#pragma unroll
            for (int r = 0; r < 4; ++r) {
                const int row = wm + r * 16 + lr;
                av[r] = *(const short8*)&sm.At[row * 64 + (((ks * 4 + quad) ^ (row & 7)) * 8)];
            }
#pragma unroll
            for (int c = 0; c < 4; ++c) {
                const int row = wn + c * 16 + lr;
                bv[c] = *(const short8*)&sm.Bt[row * 64 + (((ks * 4 + quad) ^ (row & 7)) * 8)];
            }
#pragma unroll
            for (int r = 0; r < 4; ++r)
#pragma unroll
                for (int c = 0; c < 4; ++c)
                    acc[r][c] = __builtin_amdgcn_mfma_f32_16x16x32_bf16(av[r], bv[c], acc[r][c], 0, 0, 0);
        }
        __syncthreads();
    }
}

// C/D layout col=lane&15, row=quad*4+reg  [verified m89/m91]
#define EPI_COORDS()                               \
    const int tid = threadIdx.x;                   \
    const int wid = tid >> 6;                      \
    const int lane = tid & 63;                     \
    const int quad = lane >> 4;                    \
    const int lr = lane & 15;                      \
    const int wm = (wid & 1) * 64;                 \
    const int wn = (wid >> 1) * 64;

// ---------------------------------------------------------------- phase kernels
__global__ __launch_bounds__(256, 3) void proj_kernel(
    const unsigned short* __restrict__ in_bf,
    const unsigned short* __restrict__ WqT, const unsigned short* __restrict__ WkT,
    const unsigned short* __restrict__ WvT, const unsigned short* __restrict__ WrT,
    const unsigned short* __restrict__ pe,
    const float* __restrict__ cb, const float* __restrict__ rb,
    unsigned short* __restrict__ qc, unsigned short* __restrict__ qr,
    unsigned short* __restrict__ kbf, unsigned short* __restrict__ vT,
    unsigned short* __restrict__ rk)
{
    __shared__ SMem sm;
    EPI_COORDS();
    const long TD = (long)T_ * D_;
    const long DT = (long)D_ * T_;
    f32x4 acc[4][4];
    const int t = blockIdx.x;   // 0..1599
    if (t < 1024) {                           // qc/qr (t<512) and k (t<1024)
        const int r = t & 511;
        const int it = r >> 2, jt = r & 3;
        const unsigned short* Bw = (t < 512) ? WqT : WkT;
        gemm_core(in_bf + (long)it * 128 * 512, 512, Bw + (long)jt * 128 * 512, 512, 512, sm, acc);
        const int i0 = it * 128, j0 = jt * 128;
#pragma unroll
        for (int r2 = 0; r2 < 4; ++r2)
#pragma unroll
            for (int c2 = 0; c2 < 4; ++c2) {
                const int gi = i0 + wm + r2 * 16 + quad * 4;
                const int gj = j0 + wn + c2 * 16 + lr;
#pragma unroll
                for (int tt = 0; tt < 4; ++tt) {
                    const float v = acc[r2][c2][tt];
                    const long row = gi + tt;
                    if (t < 512) {
                        qc[row * 512 + gj] = f2bf(v + cb[gj]);
                        qr[row * 512 + gj] = f2bf(v + rb[gj]);
                    } else {
                        kbf[row * 512 + gj] = f2bf(v);
                    }
                }
            }
    } else if (t < 1536) {                    // vT[b] = Wv^T @ in[b]^T
        const int r = t - 1024;
        const int z = r >> 6, rr = r & 63;
        const int it = rr >> 4, jt = rr & 15;
        const int i0 = it * 128, j0 = jt * 128;
        gemm_core(WvT + (long)i0 * 512, 512, in_bf + (long)z * TD + (long)j0 * 512, 512, 512, sm, acc);
#pragma unroll
        for (int r2 = 0; r2 < 4; ++r2)
#pragma unroll
            for (int c2 = 0; c2 < 4; ++c2) {
                const int gi = i0 + wm + r2 * 16 + quad * 4;
                const int gj = j0 + wn + c2 * 16 + lr;
#pragma unroll
                for (int tt = 0; tt < 4; ++tt)
                    vT[(long)z * DT + (long)(gi + tt) * 2048 + gj] = f2bf(acc[r2][c2][tt]);
            }
    } else {                                  // rk = pe @ Wrel
        const int r = t - 1536;
        const int it = r >> 2, jt = r & 3;
        const int i0 = it * 128, j0 = jt * 128;
        gemm_core(pe + (long)i0 * 512, 512, WrT + (long)j0 * 512, 512, 512, sm, acc);
#pragma unroll
        for (int r2 = 0; r2 < 4; ++r2)
#pragma unroll
            for (int c2 = 0; c2 < 4; ++c2) {
                const int gi = i0 + wm + r2 * 16 + quad * 4;
                const int gj = j0 + wn + c2 * 16 + lr;
#pragma unroll
                for (int tt = 0; tt < 4; ++tt)
                    rk[(long)(gi + tt) * 512 + gj] = f2bf(acc[r2][c2][tt]);
            }
    }
}

// content scores -> C8 (pre-scaled, causal tiles) and rel scores -> R8 (raw),
// one dispatch, 2176 blocks, no RMW anywhere.
__global__ __launch_bounds__(256, 3) void score_kernel(
    const unsigned short* __restrict__ qc, const unsigned short* __restrict__ qr,
    const unsigned short* __restrict__ kbf, const unsigned short* __restrict__ rk,
    float* __restrict__ C8, float* __restrict__ R8)
{
    __shared__ SMem sm;
    EPI_COORDS();
    const long TD = (long)T_ * D_;
    f32x4 acc[4][4];
    const int t0 = blockIdx.x;                // 0..2175
    if (t0 < 1088) {
        const int z = t0 / 136;
        const int r = t0 - z * 136;
        int a = (int)((sqrtf(8.f * (float)r + 1.f) - 1.f) * 0.5f);
        if ((a + 1) * (a + 2) / 2 <= r) ++a;
        if (a * (a + 1) / 2 > r) --a;
        const int b = r - a * (a + 1) / 2;    // b <= a (causal tiles)
        const int i0 = a * 128, j0 = b * 128;
        gemm_core(qc + (long)z * TD + (long)i0 * 512, 512,
                  kbf + (long)z * TD + (long)j0 * 512, 512, 512, sm, acc);
        float* Cf = C8 + (long)z * 4194304L;
#pragma unroll
        for (int r2 = 0; r2 < 4; ++r2)
#pragma unroll
            for (int c2 = 0; c2 < 4; ++c2) {
                const int gi = i0 + wm + r2 * 16 + quad * 4;
                const int gj = j0 + wn + c2 * 16 + lr;
#pragma unroll
                for (int tt = 0; tt < 4; ++tt)
                    Cf[(long)(gi + tt) * 2048 + gj] = acc[r2][c2][tt] * SC_;
            }
    } else {
        const int t2 = t0 - 1088;
        const int z = t2 / 136;
        const int r = t2 - z * 136;
        int u = (int)((sqrtf(8.f * (float)r + 1.f) - 1.f) * 0.5f);
        if ((u + 1) * (u + 2) / 2 <= r) ++u;
        if (u * (u + 1) / 2 > r) --u;
        const int v2 = r - u * (u + 1) / 2;   // v2 <= u
        const int a = u, b = 15 - u + v2;     // tiles covering p >= T-1-i
        const int i0 = a * 128, p0 = b * 128;
        gemm_core(qr + (long)z * TD + (long)i0 * 512, 512,
                  rk + (long)p0 * 512, 512, 512, sm, acc);
        float* Rf = R8 + (long)z * 4194304L;
#pragma unroll
        for (int r2 = 0; r2 < 4; ++r2)
#pragma unroll
            for (int c2 = 0; c2 < 4; ++c2) {
                const int gi = i0 + wm + r2 * 16 + quad * 4;
                const int gp = p0 + wn + c2 * 16 + lr;
#pragma unroll
                for (int tt = 0; tt < 4; ++tt)
                    Rf[(long)(gi + tt) * 2048 + gp] = acc[r2][c2][tt];
            }
    }
}

// row softmax: S[i,j] = C8[i,j] + SC*R8[i, j+(T-1-i)]; P (bf16) in place over C8.
__global__ __launch_bounds__(256) void softmax_kernel(float* __restrict__ C8,
                                                      const float* __restrict__ R8) {
    float* Cm = C8 + (long)blockIdx.y * 4194304L;
    const int i = blockIdx.x;
    const int n = i + 1;
    __shared__ float s[2048];
    __shared__ float red[8];
    const int tid = threadIdx.x;
    const int wid = tid >> 6;
    float* crow = Cm + (long)i * 2048;
    const float* rrow = R8 + (long)blockIdx.y * 4194304L + (long)i * 2048 + (2047 - i);
    float lmax = -3.0e38f;
    for (int j = tid; j < n; j += 256) {
        float v = crow[j] + rrow[j] * SC_;
        s[j] = v; lmax = fmaxf(lmax, v);
    }
    for (int o = 32; o; o >>= 1) lmax = fmaxf(lmax, __shfl_down(lmax, o));
    if ((tid & 63) == 0) red[wid] = lmax;
    __syncthreads();
    if (tid == 0) red[4] = fmaxf(fmaxf(red[0], red[1]), fmaxf(red[2], red[3]));
    __syncthreads();
    const float m = red[4];
    float lsum = 0.f;
    for (int j = tid; j < n; j += 256) { float e = __expf(s[j] - m); s[j] = e; lsum += e; }
    for (int o = 32; o; o >>= 1) lsum += __shfl_down(lsum, o);
    __syncthreads();
    if ((tid & 63) == 0) red[wid] = lsum;
    __syncthreads();
    if (tid == 0) red[4] = 1.0f / (red[0] + red[1] + red[2] + red[3]);
    __syncthreads();
    const float inv = red[4];
    unsigned short* P = (unsigned short*)Cm;          // bf16 row stride 4096
    const int iend = ((i >> 7) + 1) << 7;             // zero-pad to 128-tile edge
    for (int j = tid; j < iend; j += 256) {
        const float pv = (j < n) ? s[j] * inv : 0.f;
        P[(long)i * 4096 + j] = f2bf(pv);
    }
}

__global__ __launch_bounds__(256, 3) void pv_kernel(
    const float* __restrict__ C8, const unsigned short* __restrict__ vT,
    float* __restrict__ out)
{
    __shared__ SMem sm;
    EPI_COORDS();
    const long TD = (long)T_ * D_;
    const long DT = (long)D_ * T_;
    f32x4 acc[4][4];
    const int t = blockIdx.x;                 // 0..511
    const int z = t >> 6;
    const int rr = t & 63;
    const int it = rr >> 2, jt = rr & 3;
    const int i0 = it * 128, j0 = jt * 128;
    const int kmax = i0 + 128;                // causal K-limit (multiple of 128)
    gemm_core((const unsigned short*)(C8 + (long)z * 4194304L) + (long)i0 * 4096, 4096,
              vT + (long)z * DT + (long)j0 * 2048, 2048, kmax, sm, acc);
#pragma unroll
    for (int r2 = 0; r2 < 4; ++r2)
#pragma unroll
        for (int c2 = 0; c2 < 4; ++c2) {
            const int gi = i0 + wm + r2 * 16 + quad * 4;
            const int gj = j0 + wn + c2 * 16 + lr;
#pragma unroll
            for (int tt = 0; tt < 4; ++tt)
                out[(long)z * TD + (long)(gi + tt) * 512 + gj] = acc[r2][c2][tt];
        }
}

// ---------------------------------------------------------------- launcher
extern "C" void kernel_launch(void* const* d_in, const int* in_sizes, int n_in,
                              void* d_out, int out_size, void* d_ws, size_t ws_size,
                              hipStream_t stream) {
    (void)in_sizes; (void)n_in; (void)out_size; (void)ws_size;
    const float* inputs = (const float*)d_in[0];
    const float* Wq = (const float*)d_in[1];
    const float* Wk = (const float*)d_in[2];
    const float* Wv = (const float*)d_in[3];
    const float* Wrel = (const float*)d_in[4];
    const float* cb = (const float*)d_in[5];
    const float* rb = (const float*)d_in[6];
    float* out = (float*)d_out;

    // workspace layout (~357 MB)
    char* ws = (char*)d_ws;
    unsigned short* in_bf = (unsigned short*)ws;                   // 16384x512
    unsigned short* WqT = (unsigned short*)(ws + 16777216);
    unsigned short* WkT = WqT + 262144;
    unsigned short* WvT = WkT + 262144;
    unsigned short* WrT = WvT + 262144;
    unsigned short* pe  = WrT + 262144;                            // 2048x512
    unsigned short* qc  = pe + 1048576;                            // 16384x512
    unsigned short* qr  = qc + 8388608;
    unsigned short* kbf = qr + 8388608;
    unsigned short* vT  = kbf + 8388608;                           // 8 x 512x2048
    unsigned short* rk  = vT + 8388608;                            // 2048x512
    float* C8 = (float*)(rk + 1048576);                            // 8 x 2048x2048 f32
    float* R8 = C8 + 33554432;                                     // 8 x 2048x2048 f32

    prep_all<<<dim3(10240), 256, 0, stream>>>(inputs, Wq, Wk, Wv, Wrel,
                                              in_bf, WqT, WkT, WvT, WrT, pe);
    proj_kernel<<<dim3(1600), 256, 0, stream>>>(in_bf, WqT, WkT, WvT, WrT, pe, cb, rb,
                                                qc, qr, kbf, vT, rk);
    score_kernel<<<dim3(2176), 256, 0, stream>>>(qc, qr, kbf, rk, C8, R8);
    softmax_kernel<<<dim3(2048, 8), 256, 0, stream>>>(C8, R8);
    pv_kernel<<<dim3(512), 256, 0, stream>>>(C8, vT, out);
}

// Round 7
// 372.744 us; speedup vs baseline: 2.4683x; 1.0509x over previous
//
#include <hip/hip_runtime.h>

typedef __attribute__((ext_vector_type(8))) short short8;
typedef __attribute__((ext_vector_type(4))) float f32x4;
typedef __attribute__((ext_vector_type(4))) float fvec4;
typedef __attribute__((ext_vector_type(4))) unsigned short us4;

#define T_ 2048
#define D_ 512
#define SC_ 0.04419417382415922f   // 1/sqrt(512)

__device__ __forceinline__ unsigned short f2bf(float f) {
    unsigned int u = __float_as_uint(f);
    u += 0x7fffu + ((u >> 16) & 1u);
    return (unsigned short)(u >> 16);
}

// async global->LDS, 16B per lane; LDS dest = wave-uniform base + lane*16
__device__ __forceinline__ void gload16(const void* g, void* l) {
    __builtin_amdgcn_global_load_lds((const __attribute__((address_space(1))) unsigned int*)g,
                                     (__attribute__((address_space(3))) unsigned int*)l,
                                     16, 0, 0);
}

// ---------------------------------------------------------------- merged prep
__global__ __launch_bounds__(256) void prep_all(
    const float* __restrict__ in_f,
    const float* __restrict__ Wq, const float* __restrict__ Wk,
    const float* __restrict__ Wv, const float* __restrict__ Wr,
    unsigned short* __restrict__ in_bf,
    unsigned short* __restrict__ WqT, unsigned short* __restrict__ WkT,
    unsigned short* __restrict__ WvT, unsigned short* __restrict__ WrT,
    unsigned short* __restrict__ pe)
{
    const int bb = blockIdx.x;
    const int tid = threadIdx.x;
    if (bb < 8192) {
        const int idx = bb * 256 + tid;
        fvec4 v = ((const fvec4*)in_f)[idx];
        us4 o;
        o.x = f2bf(v.x); o.y = f2bf(v.y); o.z = f2bf(v.z); o.w = f2bf(v.w);
        ((us4*)in_bf)[idx] = o;
    } else if (bb < 9216) {
        __shared__ float wt[32][33];              // padded: no bank conflicts
        const int t = bb - 8192;                  // 0..1023
        const int w = t >> 8, tile = t & 255;
        const int tr = (tile >> 4) * 32, tc = (tile & 15) * 32;
        const float* W = (w == 0) ? Wq : (w == 1) ? Wk : (w == 2) ? Wv : Wr;
        unsigned short* WT = (w == 0) ? WqT : (w == 1) ? WkT : (w == 2) ? WvT : WrT;
        const int r0 = tid >> 5, c0 = tid & 31;
#pragma unroll
        for (int p = 0; p < 4; ++p)
            wt[r0 + 8 * p][c0] = W[(long)(tr + r0 + 8 * p) * 512 + tc + c0];
        __syncthreads();
#pragma unroll
        for (int p = 0; p < 4; ++p)
            WT[(long)(tc + r0 + 8 * p) * 512 + tr + c0] = f2bf(wt[c0][r0 + 8 * p]);
    } else {
        const int idx = (bb - 9216) * 256 + tid;  // 0..262143 us4 chunks
        const int o = idx * 4;
        const int rpos = o >> 9;
        us4 ov;
#pragma unroll
        for (int e = 0; e < 4; ++e) {
            const int c = (o + e) & 511;
            const int ci = (c < 256) ? c : c - 256;
            const float dv = expf((float)ci * -0.03611898183128701f);  // -log(1e4)/255
            const float ang = (float)rpos * dv;
            ((unsigned short*)&ov)[e] = f2bf((c < 256) ? sinf(ang) : cosf(ang));
        }
        ((us4*)pe)[idx] = ov;
    }
}

// ---------------------------------------------------------------- GEMM core
// BK=64. LDS tile [128][64] bf16 (16 KB each). Element (row,c) lives in 16B
// chunk (row, (c/8) ^ (row&7)) — XOR swizzle: 0 bank conflicts (verified R5/R6).
struct __align__(16) SMem {
    unsigned short At[128 * 64];   // 16 KB
    unsigned short Bt[128 * 64];   // 16 KB
};

__device__ __forceinline__ void gemm_core(const unsigned short* __restrict__ A, long lda,
                                          const unsigned short* __restrict__ B, long ldb,
                                          int kmax, SMem& sm, f32x4 (&acc)[4][4]) {
    const int tid = threadIdx.x;
    const int wid = tid >> 6;
    const int lane = tid & 63;
    const int quad = lane >> 4;
    const int lr = lane & 15;
    const int wm = (wid & 1) * 64;
    const int wn = (wid >> 1) * 64;
#pragma unroll
    for (int r = 0; r < 4; ++r)
#pragma unroll
        for (int c = 0; c < 4; ++c) acc[r][c] = (f32x4){0.f, 0.f, 0.f, 0.f};

    const int sr = tid >> 3;                             // staging row 0..31
    const int l8 = ((tid & 7) ^ (sr & 7)) * 8;           // swizzled source chunk
    const unsigned short* Ag = A + (long)sr * lda + l8;
    const unsigned short* Bg = B + (long)sr * ldb + l8;

    for (int kk = 0; kk < kmax; kk += 64) {
#pragma unroll
        for (int c = 0; c < 4; ++c) {                    // rows 32c..32c+31
            gload16(Ag + (long)(32 * c) * lda + kk, &sm.At[c * 2048 + wid * 512]);
            gload16(Bg + (long)(32 * c) * ldb + kk, &sm.Bt[c * 2048 + wid * 512]);
        }
        __syncthreads();
#pragma unroll
        for (int ks = 0; ks < 2; ++ks) {
            short8 av[4], bv[4];
#pragma unroll
            for (int r = 0; r < 4; ++r) {
                const int row = wm + r * 16 + lr;
                av[r] = *(const short8*)&sm.At[row * 64 + (((ks * 4 + quad) ^ (row & 7)) * 8)];
            }
#pragma unroll
            for (int c = 0; c < 4; ++c) {
                const int row = wn + c * 16 + lr;
                bv[c] = *(const short8*)&sm.Bt[row * 64 + (((ks * 4 + quad) ^ (row & 7)) * 8)];
            }
#pragma unroll
            for (int r = 0; r < 4; ++r)
#pragma unroll
                for (int c = 0; c < 4; ++c)
                    acc[r][c] = __builtin_amdgcn_mfma_f32_16x16x32_bf16(av[r], bv[c], acc[r][c], 0, 0, 0);
        }
        __syncthreads();
    }
}

// C/D layout col=lane&15, row=quad*4+reg  [verified m89/m91]
#define EPI_COORDS()                               \
    const int tid = threadIdx.x;                   \
    const int wid = tid >> 6;                      \
    const int lane = tid & 63;                     \
    const int quad = lane >> 4;                    \
    const int lr = lane & 15;                      \
    const int wm = (wid & 1) * 64;                 \
    const int wn = (wid >> 1) * 64;

// ---------------------------------------------------------------- phase kernels
__global__ __launch_bounds__(256, 3) void proj_kernel(
    const unsigned short* __restrict__ in_bf,
    const unsigned short* __restrict__ WqT, const unsigned short* __restrict__ WkT,
    const unsigned short* __restrict__ WvT, const unsigned short* __restrict__ WrT,
    const unsigned short* __restrict__ pe,
    const float* __restrict__ cb, const float* __restrict__ rb,
    unsigned short* __restrict__ qc, unsigned short* __restrict__ qr,
    unsigned short* __restrict__ kbf, unsigned short* __restrict__ vT,
    unsigned short* __restrict__ rk)
{
    __shared__ SMem sm;
    EPI_COORDS();
    const long TD = (long)T_ * D_;
    const long DT = (long)D_ * T_;
    f32x4 acc[4][4];
    const int t = blockIdx.x;   // 0..1599
    if (t < 1024) {                           // qc/qr (t<512) and k (t<1024)
        const int r = t & 511;
        const int it = r >> 2, jt = r & 3;
        const unsigned short* Bw = (t < 512) ? WqT : WkT;
        gemm_core(in_bf + (long)it * 128 * 512, 512, Bw + (long)jt * 128 * 512, 512, 512, sm, acc);
        const int i0 = it * 128, j0 = jt * 128;
#pragma unroll
        for (int r2 = 0; r2 < 4; ++r2)
#pragma unroll
            for (int c2 = 0; c2 < 4; ++c2) {
                const int gi = i0 + wm + r2 * 16 + quad * 4;
                const int gj = j0 + wn + c2 * 16 + lr;
#pragma unroll
                for (int tt = 0; tt < 4; ++tt) {
                    const float v = acc[r2][c2][tt];
                    const long row = gi + tt;
                    if (t < 512) {
                        qc[row * 512 + gj] = f2bf(v + cb[gj]);
                        qr[row * 512 + gj] = f2bf(v + rb[gj]);
                    } else {
                        kbf[row * 512 + gj] = f2bf(v);
                    }
                }
            }
    } else if (t < 1536) {                    // vT[b] = Wv^T @ in[b]^T
        const int r = t - 1024;
        const int z = r >> 6, rr = r & 63;
        const int it = rr >> 4, jt = rr & 15;
        const int i0 = it * 128, j0 = jt * 128;
        gemm_core(WvT + (long)i0 * 512, 512, in_bf + (long)z * TD + (long)j0 * 512, 512, 512, sm, acc);
#pragma unroll
        for (int r2 = 0; r2 < 4; ++r2)
#pragma unroll
            for (int c2 = 0; c2 < 4; ++c2) {
                const int gi = i0 + wm + r2 * 16 + quad * 4;
                const int gj = j0 + wn + c2 * 16 + lr;
#pragma unroll
                for (int tt = 0; tt < 4; ++tt)
                    vT[(long)z * DT + (long)(gi + tt) * 2048 + gj] = f2bf(acc[r2][c2][tt]);
            }
    } else {                                  // rk = pe @ Wrel
        const int r = t - 1536;
        const int it = r >> 2, jt = r & 3;
        const int i0 = it * 128, j0 = jt * 128;
        gemm_core(pe + (long)i0 * 512, 512, WrT + (long)j0 * 512, 512, 512, sm, acc);
#pragma unroll
        for (int r2 = 0; r2 < 4; ++r2)
#pragma unroll
            for (int c2 = 0; c2 < 4; ++c2) {
                const int gi = i0 + wm + r2 * 16 + quad * 4;
                const int gj = j0 + wn + c2 * 16 + lr;
#pragma unroll
                for (int tt = 0; tt < 4; ++tt)
                    rk[(long)(gi + tt) * 512 + gj] = f2bf(acc[r2][c2][tt]);
            }
    }
}

// content scores -> C8 (pre-scaled, causal tiles) and rel scores -> R8 (raw).
// XCD-aware: z = blockIdx & 7 so each XCD works one batch (4 MB working set
// fits per-XCD L2); content jobs dispatch before rel jobs per XCD.
__global__ __launch_bounds__(256, 3) void score_kernel(
    const unsigned short* __restrict__ qc, const unsigned short* __restrict__ qr,
    const unsigned short* __restrict__ kbf, const unsigned short* __restrict__ rk,
    float* __restrict__ C8, float* __restrict__ R8)
{
    __shared__ SMem sm;
    EPI_COORDS();
    const long TD = (long)T_ * D_;
    f32x4 acc[4][4];
    const int z = blockIdx.x & 7;             // XCD cluster by batch
    const int rr = blockIdx.x >> 3;           // 0..271
    if (rr < 136) {
        const int r = rr;
        int a = (int)((sqrtf(8.f * (float)r + 1.f) - 1.f) * 0.5f);
        if ((a + 1) * (a + 2) / 2 <= r) ++a;
        if (a * (a + 1) / 2 > r) --a;
        const int b = r - a * (a + 1) / 2;    // b <= a (causal tiles)
        const int i0 = a * 128, j0 = b * 128;
        gemm_core(qc + (long)z * TD + (long)i0 * 512, 512,
                  kbf + (long)z * TD + (long)j0 * 512, 512, 512, sm, acc);
        float* Cf = C8 + (long)z * 4194304L;
#pragma unroll
        for (int r2 = 0; r2 < 4; ++r2)
#pragma unroll
            for (int c2 = 0; c2 < 4; ++c2) {
                const int gi = i0 + wm + r2 * 16 + quad * 4;
                const int gj = j0 + wn + c2 * 16 + lr;
#pragma unroll
                for (int tt = 0; tt < 4; ++tt)
                    Cf[(long)(gi + tt) * 2048 + gj] = acc[r2][c2][tt] * SC_;
            }
    } else {
        const int r = rr - 136;
        int u = (int)((sqrtf(8.f * (float)r + 1.f) - 1.f) * 0.5f);
        if ((u + 1) * (u + 2) / 2 <= r) ++u;
        if (u * (u + 1) / 2 > r) --u;
        const int v2 = r - u * (u + 1) / 2;   // v2 <= u
        const int a = u, b = 15 - u + v2;     // tiles covering p >= T-1-i
        const int i0 = a * 128, p0 = b * 128;
        gemm_core(qr + (long)z * TD + (long)i0 * 512, 512,
                  rk + (long)p0 * 512, 512, 512, sm, acc);
        float* Rf = R8 + (long)z * 4194304L;
#pragma unroll
        for (int r2 = 0; r2 < 4; ++r2)
#pragma unroll
            for (int c2 = 0; c2 < 4; ++c2) {
                const int gi = i0 + wm + r2 * 16 + quad * 4;
                const int gp = p0 + wn + c2 * 16 + lr;
#pragma unroll
                for (int tt = 0; tt < 4; ++tt)
                    Rf[(long)(gi + tt) * 2048 + gp] = acc[r2][c2][tt];
            }
    }
}

// row softmax: S[i,j] = C8[i,j] + SC*R8[i, j+(T-1-i)]; P (bf16) in place over C8.
// 8 strided rows per block (i = bx + 256*s) for launch amortization + balance.
__global__ __launch_bounds__(256) void softmax_kernel(float* __restrict__ C8,
                                                      const float* __restrict__ R8) {
    float* Cm = C8 + (long)blockIdx.y * 4194304L;
    const float* Rm = R8 + (long)blockIdx.y * 4194304L;
    __shared__ float s[2048];
    __shared__ float red[8];
    const int tid = threadIdx.x;
    const int wid = tid >> 6;
    for (int ss = 0; ss < 8; ++ss) {
        const int i = blockIdx.x + 256 * ss;
        const int n = i + 1;
        float* crow = Cm + (long)i * 2048;
        const float* rrow = Rm + (long)i * 2048 + (2047 - i);
        __syncthreads();                              // s[] reuse across rows
        float lmax = -3.0e38f;
        for (int j = tid; j < n; j += 256) {
            float v = crow[j] + rrow[j] * SC_;
            s[j] = v; lmax = fmaxf(lmax, v);
        }
        for (int o = 32; o; o >>= 1) lmax = fmaxf(lmax, __shfl_down(lmax, o));
        if ((tid & 63) == 0) red[wid] = lmax;
        __syncthreads();
        if (tid == 0) red[4] = fmaxf(fmaxf(red[0], red[1]), fmaxf(red[2], red[3]));
        __syncthreads();
        const float m = red[4];
        float lsum = 0.f;
        for (int j = tid; j < n; j += 256) { float e = __expf(s[j] - m); s[j] = e; lsum += e; }
        for (int o = 32; o; o >>= 1) lsum += __shfl_down(lsum, o);
        __syncthreads();
        if ((tid & 63) == 0) red[wid] = lsum;
        __syncthreads();
        if (tid == 0) red[4] = 1.0f / (red[0] + red[1] + red[2] + red[3]);
        __syncthreads();
        const float inv = red[4];
        unsigned short* P = (unsigned short*)Cm;      // bf16 row stride 4096
        const int iend = ((i >> 7) + 1) << 7;         // zero-pad to 128-tile edge
        for (int j = tid; j < iend; j += 256) {
            const float pv = (j < n) ? s[j] * inv : 0.f;
            P[(long)i * 4096 + j] = f2bf(pv);
        }
    }
}

// out = P @ V. XCD-aware z clustering + big-K tiles dispatched first.
__global__ __launch_bounds__(256, 3) void pv_kernel(
    const float* __restrict__ C8, const unsigned short* __restrict__ vT,
    float* __restrict__ out)
{
    __shared__ SMem sm;
    EPI_COORDS();
    const long TD = (long)T_ * D_;
    const long DT = (long)D_ * T_;
    f32x4 acc[4][4];
    const int z = blockIdx.x & 7;             // XCD cluster by batch
    const int q = blockIdx.x >> 3;            // 0..63
    const int it = 15 - (q >> 2);             // big K first
    const int jt = q & 3;
    const int i0 = it * 128, j0 = jt * 128;
    const int kmax = i0 + 128;                // causal K-limit (multiple of 128)
    gemm_core((const unsigned short*)(C8 + (long)z * 4194304L) + (long)i0 * 4096, 4096,
              vT + (long)z * DT + (long)j0 * 2048, 2048, kmax, sm, acc);
#pragma unroll
    for (int r2 = 0; r2 < 4; ++r2)
#pragma unroll
        for (int c2 = 0; c2 < 4; ++c2) {
            const int gi = i0 + wm + r2 * 16 + quad * 4;
            const int gj = j0 + wn + c2 * 16 + lr;
#pragma unroll
            for (int tt = 0; tt < 4; ++tt)
                out[(long)z * TD + (long)(gi + tt) * 512 + gj] = acc[r2][c2][tt];
        }
}

// ---------------------------------------------------------------- launcher
extern "C" void kernel_launch(void* const* d_in, const int* in_sizes, int n_in,
                              void* d_out, int out_size, void* d_ws, size_t ws_size,
                              hipStream_t stream) {
    (void)in_sizes; (void)n_in; (void)out_size; (void)ws_size;
    const float* inputs = (const float*)d_in[0];
    const float* Wq = (const float*)d_in[1];
    const float* Wk = (const float*)d_in[2];
    const float* Wv = (const float*)d_in[3];
    const float* Wrel = (const float*)d_in[4];
    const float* cb = (const float*)d_in[5];
    const float* rb = (const float*)d_in[6];
    float* out = (float*)d_out;

    // workspace layout (~357 MB)
    char* ws = (char*)d_ws;
    unsigned short* in_bf = (unsigned short*)ws;                   // 16384x512
    unsigned short* WqT = (unsigned short*)(ws + 16777216);
    unsigned short* WkT = WqT + 262144;
    unsigned short* WvT = WkT + 262144;
    unsigned short* WrT = WvT + 262144;
    unsigned short* pe  = WrT + 262144;                            // 2048x512
    unsigned short* qc  = pe + 1048576;                            // 16384x512
    unsigned short* qr  = qc + 8388608;
    unsigned short* kbf = qr + 8388608;
    unsigned short* vT  = kbf + 8388608;                           // 8 x 512x2048
    unsigned short* rk  = vT + 8388608;                            // 2048x512
    float* C8 = (float*)(rk + 1048576);                            // 8 x 2048x2048 f32
    float* R8 = C8 + 33554432;                                     // 8 x 2048x2048 f32

    prep_all<<<dim3(10240), 256, 0, stream>>>(inputs, Wq, Wk, Wv, Wrel,
                                              in_bf, WqT, WkT, WvT, WrT, pe);
    proj_kernel<<<dim3(1600), 256, 0, stream>>>(in_bf, WqT, WkT, WvT, WrT, pe, cb, rb,
                                                qc, qr, kbf, vT, rk);
    score_kernel<<<dim3(2176), 256, 0, stream>>>(qc, qr, kbf, rk, C8, R8);
    softmax_kernel<<<dim3(256, 8), 256, 0, stream>>>(C8, R8);
    pv_kernel<<<dim3(512), 256, 0, stream>>>(C8, vT, out);
}